// Round 14
// baseline (584.757 us; speedup 1.0000x reference)
//
#include <hip/hip_runtime.h>

#define B_ 2
#define T_ 2048
#define D_ 2048
#define H_ 16
#define DK_ 96
#define DV_ 192
#define KEYD 1536
#define VALD 3072
#define NPROJ 9216
#define PQK 6144     // Pqkv row width (q|k|v)
#define KS_ 4
#define C_ 64
#define NC_ 32       // T_/C_

typedef unsigned short u16;
typedef unsigned int u32;
typedef __bf16 bf16x8 __attribute__((ext_vector_type(8)));
typedef float f32x4 __attribute__((ext_vector_type(4)));

// ---------- helpers ----------
__device__ __forceinline__ u16 f2bf(float f) {
  unsigned u = __float_as_uint(f);
  u += 0x7FFF + ((u >> 16) & 1);
  return (u16)(u >> 16);
}
__device__ __forceinline__ float bf2f(u16 v) { return __uint_as_float((unsigned)v << 16); }
__device__ __forceinline__ float bflo(u32 w) { return __uint_as_float(w << 16); }
__device__ __forceinline__ float bfhi(u32 w) { return __uint_as_float(w & 0xFFFF0000u); }

__device__ __forceinline__ void gll16(const void* g, void* lds) {
  __builtin_amdgcn_global_load_lds(
      (const __attribute__((address_space(1))) void*)g,
      (__attribute__((address_space(3))) void*)lds, 16, 0, 0);
}

// ---------- casts / transposes ----------
__device__ __forceinline__ void tc_body(const float* __restrict__ src,
                                        u16* __restrict__ dst, int R, int C,
                                        int bx, int by, int tid) {
  __shared__ float tile[32][33];
  int tx = tid & 31, ty = tid >> 5;
  int c0 = bx * 32, r0 = by * 32;
#pragma unroll
  for (int j = 0; j < 4; ++j)
    tile[ty + j * 8][tx] = src[(size_t)(r0 + ty + j * 8) * C + c0 + tx];
  __syncthreads();
#pragma unroll
  for (int j = 0; j < 4; ++j)
    dst[(size_t)(c0 + ty + j * 8) * R + r0 + tx] = f2bf(tile[tx][ty + j * 8]);
}

__global__ __launch_bounds__(256) void transpose_cast(const float* __restrict__ src,
                                                      u16* __restrict__ dst, int R, int C) {
  tc_body(src, dst, R, C, blockIdx.x, blockIdx.y, threadIdx.x);
}

// fused: transpose Wq|Wk|Wv|Wg into WT + cast x -> xb (bit-identical to separate launches)
__global__ __launch_bounds__(256) void transpose_cast4(const float* __restrict__ Wq,
    const float* __restrict__ Wk, const float* __restrict__ Wv,
    const float* __restrict__ Wg, u16* __restrict__ WT,
    const float* __restrict__ x, u16* __restrict__ xb, int n4) {
  int id = blockIdx.x;
  if (id < 3072) {
    tc_body(Wq, WT, 2048, 1536, id % 48, id / 48, threadIdx.x);
  } else if (id < 6144) {
    id -= 3072;
    tc_body(Wk, WT + (size_t)1536 * 2048, 2048, 1536, id % 48, id / 48, threadIdx.x);
  } else if (id < 12288) {
    id -= 6144;
    tc_body(Wv, WT + (size_t)3072 * 2048, 2048, 3072, id % 96, id / 96, threadIdx.x);
  } else if (id < 18432) {
    id -= 12288;
    tc_body(Wg, WT + (size_t)6144 * 2048, 2048, 3072, id % 96, id / 96, threadIdx.x);
  } else {
    int i = (id - 18432) * 256 + threadIdx.x;
    if (i < n4) {
      float4 v = reinterpret_cast<const float4*>(x)[i];
      ushort4 o;
      o.x = f2bf(v.x); o.y = f2bf(v.y); o.z = f2bf(v.z); o.w = f2bf(v.w);
      reinterpret_cast<ushort4*>(xb)[i] = o;
    }
  }
}

// ============ 256x256 BK=64 GEMM, 4-phase/tile (round-10 proven, 200 us) ============
template <int OUT16>
__global__ __launch_bounds__(512, 2) void gemm256(const u16* __restrict__ A,
    const u16* __restrict__ BT, u16* __restrict__ C0, u16* __restrict__ C1,
    float* __restrict__ Cf, int M, int N, int K, int nsplit, int s0, int s1) {
  __shared__ u16 LA[2][256 * 64];
  __shared__ u16 LB[2][256 * 64];
  const int tid = threadIdx.x, wave = tid >> 6, lane = tid & 63;
  const int l15 = lane & 15, l16 = lane >> 4, x7 = l15 & 7;
  const int wr = wave >> 2, wc = wave & 3;
  const int m0 = blockIdx.y * 256, n0 = blockIdx.x * 256;
  const int r8 = lane >> 3;
  const int csrc = ((lane & 7) ^ r8) << 3;    // pre-swizzled source elem offset
  const int NKT = K >> 6;
  f32x4 acc[8][4] = {};

// A staged in mh-interleaved halves: half 0 = rows {0-63,128-191}, half 1 = {64-127,192-255}
#define STG_A(p, kt, half) { \
    const u16* As_ = A + (size_t)m0 * K + (size_t)(kt) * 64; \
    _Pragma("unroll") \
    for (int g = 0; g < 2; ++g) { \
      int rowb = g * 128 + (half) * 64 + wave * 8; \
      gll16(As_ + (size_t)(rowb + r8) * K + csrc, (char*)&LA[p][0] + rowb * 128); \
    } \
  }
#define STG_B(p, kt) { \
    const u16* Bs_ = BT + (size_t)n0 * K + (size_t)(kt) * 64; \
    _Pragma("unroll") \
    for (int j = 0; j < 4; ++j) { \
      int rowb = j * 64 + wave * 8; \
      gll16(Bs_ + (size_t)(rowb + r8) * K + csrc, (char*)&LB[p][0] + rowb * 128); \
    } \
  }

#define LDA8(p, mh, dst) { \
    _Pragma("unroll") \
    for (int mi = 0; mi < 4; ++mi) \
      _Pragma("unroll") \
      for (int kk = 0; kk < 2; ++kk) { \
        int row = wr * 128 + (mh) * 64 + mi * 16 + l15; \
        dst[mi * 2 + kk] = *(const bf16x8*)((const char*)&LA[p][0] + row * 128 + (((kk * 4 + l16) ^ x7) << 4)); \
      } \
  }
#define LDB4(p, nh, dst) { \
    _Pragma("unroll") \
    for (int ni = 0; ni < 2; ++ni) \
      _Pragma("unroll") \
      for (int kk = 0; kk < 2; ++kk) { \
        int row = wc * 64 + (nh) * 32 + ni * 16 + l15; \
        dst[ni * 2 + kk] = *(const bf16x8*)((const char*)&LB[p][0] + row * 128 + (((kk * 4 + l16) ^ x7) << 4)); \
      } \
  }

#define MMQ(AF, BF, mbase, nbase) { \
    __builtin_amdgcn_s_setprio(1); \
    _Pragma("unroll") \
    for (int mi = 0; mi < 4; ++mi) \
      _Pragma("unroll") \
      for (int ni = 0; ni < 2; ++ni) \
        _Pragma("unroll") \
        for (int kk = 0; kk < 2; ++kk) \
          acc[(mbase) + mi][(nbase) + ni] = __builtin_amdgcn_mfma_f32_16x16x32_bf16( \
              AF[mi * 2 + kk], BF[ni * 2 + kk], acc[(mbase) + mi][(nbase) + ni], 0, 0, 0); \
    __builtin_amdgcn_s_setprio(0); \
  }

#define BARR() __builtin_amdgcn_s_barrier()

  // prologue: stage tiles 0,1 fully; wait tile0 resident (tile1 stays in flight)
  STG_A(0, 0, 0); STG_A(0, 0, 1); STG_B(0, 0);
  if (NKT > 1) {
    STG_A(1, 1, 0); STG_A(1, 1, 1); STG_B(1, 1);
    asm volatile("s_waitcnt vmcnt(8)" ::: "memory");
  } else {
    asm volatile("s_waitcnt vmcnt(0)" ::: "memory");
  }
  BARR();

  bf16x8 afA[8], afB[8], bf0[4], bf1[4];
  for (int c = 0; c < NKT; ++c) {
    const int p = c & 1;
    const bool stg = (c + 2 < NKT);
    // ---- ph0: Q00 ----
    LDA8(p, 0, afA); LDB4(p, 0, bf0);
    BARR();
    MMQ(afA, bf0, 0, 0);
    BARR();
    // ---- ph1: Q01 ---- (stage A-half0 of c+2: A-mh0 rows read only at ph0)
    LDB4(p, 1, bf1);
    if (stg) STG_A(p, c + 2, 0);
    BARR();
    MMQ(afA, bf1, 0, 2);
    BARR();
    // ---- ph2: Q11 ---- (stage B full of c+2: B rows read only at ph0/ph1)
    LDA8(p, 1, afB);
    if (stg) STG_B(p, c + 2);
    BARR();
    MMQ(afB, bf1, 4, 2);
    BARR();
    // ---- ph3: Q10 ---- (stage A-half1; counted vmcnt once per tile)
    if (stg) {
      STG_A(p, c + 2, 1);
      asm volatile("s_waitcnt vmcnt(8)" ::: "memory");
    } else if (c + 1 < NKT) {
      asm volatile("s_waitcnt vmcnt(0)" ::: "memory");
    }
    BARR();
    MMQ(afB, bf0, 4, 0);
    BARR();
  }

#pragma unroll
  for (int mi = 0; mi < 8; ++mi)
#pragma unroll
    for (int ni = 0; ni < 4; ++ni)
#pragma unroll
      for (int j = 0; j < 4; ++j) {
        int row = m0 + wr * 128 + mi * 16 + l16 * 4 + j;
        int col = n0 + wc * 64 + ni * 16 + l15;
        float v = acc[mi][ni][j];
        if (OUT16) {
          if (col < nsplit) C0[(size_t)row * s0 + col] = f2bf(v);
          else              C1[(size_t)row * s1 + col - nsplit] = f2bf(v);
        } else {
          Cf[(size_t)row * N + col] = v;
        }
      }
#undef STG_A
#undef STG_B
#undef LDA8
#undef LDB4
#undef MMQ
#undef BARR
}

// ---------- bf16 MFMA GEMM (m97 structure, for gemm2): C = A[M,K] * BT[N,K]^T ----------
template <int OUT16>
__global__ __launch_bounds__(256) void gemm_bt(const u16* __restrict__ A,
                                               const u16* __restrict__ BT,
                                               u16* __restrict__ C0, u16* __restrict__ C1,
                                               float* __restrict__ Cf,
                                               int M, int N, int K, int nsplit, int s0, int s1) {
  __shared__ u16 As[128 * 32];
  __shared__ u16 Bs[128 * 32];
  int tid = threadIdx.x;
  int wave = tid >> 6, lane = tid & 63;
  int l15 = lane & 15, l16 = lane >> 4;
  int m0 = blockIdx.y * 128, n0 = blockIdx.x * 128;
  int wm = (wave >> 1) * 64, wn = (wave & 1) * 64;
  f32x4 acc[4][4] = {};
  int nkt = K >> 5;
  for (int kt = 0; kt < nkt; ++kt) {
    int k0 = kt << 5;
    __syncthreads();
#pragma unroll
    for (int rr = 0; rr < 2; ++rr) {
      int idx = tid + rr * 256;
      int row = idx >> 2, kc8 = (idx & 3) * 8;
      unsigned loff = (unsigned)(rr * 256 + wave * 64) * 16;
      gll16(A + (size_t)(m0 + row) * K + k0 + kc8, (char*)As + loff);
      gll16(BT + (size_t)(n0 + row) * K + k0 + kc8, (char*)Bs + loff);
    }
    __syncthreads();
    bf16x8 af[4], bfr[4];
#pragma unroll
    for (int i = 0; i < 4; ++i)
      af[i] = *reinterpret_cast<const bf16x8*>(&As[(wm + i * 16 + l15) * 32 + l16 * 8]);
#pragma unroll
    for (int i = 0; i < 4; ++i)
      bfr[i] = *reinterpret_cast<const bf16x8*>(&Bs[(wn + i * 16 + l15) * 32 + l16 * 8]);
#pragma unroll
    for (int mi = 0; mi < 4; ++mi)
#pragma unroll
      for (int ni = 0; ni < 4; ++ni)
        acc[mi][ni] = __builtin_amdgcn_mfma_f32_16x16x32_bf16(af[mi], bfr[ni], acc[mi][ni], 0, 0, 0);
  }
#pragma unroll
  for (int mi = 0; mi < 4; ++mi)
#pragma unroll
    for (int ni = 0; ni < 4; ++ni)
#pragma unroll
      for (int j = 0; j < 4; ++j) {
        int row = m0 + wm + mi * 16 + l16 * 4 + j;
        int col = n0 + wn + ni * 16 + l15;
        if (OUT16) {
          if (col < nsplit) C0[(size_t)row * s0 + col] = f2bf(acc[mi][ni][j]);
          else              C1[(size_t)row * s1 + col - nsplit] = f2bf(acc[mi][ni][j]);
        } else {
          Cf[(size_t)row * N + col] = acc[mi][ni][j];
        }
      }
}

// ---------- beta / g projections ----------
__global__ __launch_bounds__(256) void proj_bg(const float* __restrict__ x,
    const float* __restrict__ Wb, const float* __restrict__ Wa,
    const float* __restrict__ A_log, const float* __restrict__ dt_bias,
    float* __restrict__ beta, float* __restrict__ gg) {
  __shared__ float xs[4 * 2048];
  __shared__ float red[4][32][8];
  int tid = threadIdx.x;
  int r0 = blockIdx.x * 4;
  for (int i = tid; i < 4 * 2048; i += 256)
    xs[i] = x[(size_t)r0 * D_ + i];
  __syncthreads();
  int colg = tid & 31, ks = tid >> 5;
  const float* W = (colg < 16) ? Wb : Wa;
  int wc = colg & 15;
  float p0 = 0, p1 = 0, p2 = 0, p3 = 0;
  int kbeg = ks * 256;
  for (int k = kbeg; k < kbeg + 256; ++k) {
    float wv = W[k * H_ + wc];
    p0 += xs[k] * wv;
    p1 += xs[2048 + k] * wv;
    p2 += xs[4096 + k] * wv;
    p3 += xs[6144 + k] * wv;
  }
  red[0][colg][ks] = p0; red[1][colg][ks] = p1;
  red[2][colg][ks] = p2; red[3][colg][ks] = p3;
  __syncthreads();
  if (tid < 128) {
    int row = tid >> 5, col = tid & 31;
    float d = 0;
#pragma unroll
    for (int i = 0; i < 8; ++i) d += red[row][col][i];
    int r = r0 + row;
    if (col < 16) {
      beta[(size_t)r * H_ + col] = 1.f / (1.f + __expf(-d));
    } else {
      int hh = col - 16;
      float z = d + dt_bias[hh];
      float sp = (z > 20.f) ? z : log1pf(__expf(z));
      gg[(size_t)r * H_ + hh] = -__expf(A_log[hh]) * sp;
    }
  }
}

// ---------- fused conv(KS=4)+SiLU (+L2norm for q,k), LDS-staged rows ----------
__global__ __launch_bounds__(256) void conv_qkv(const u16* __restrict__ Pqkv,
    const float* __restrict__ wq, const float* __restrict__ wk, const float* __restrict__ wv,
    u16* __restrict__ qc, u16* __restrict__ kc, u16* __restrict__ vc) {
  __shared__ __align__(16) u16 rows[4][PQK];   // 48 KB
  int bt = blockIdx.x;
  int t = bt & (T_ - 1);
  int tid = threadIdx.x, h = tid >> 4, li = tid & 15;
#pragma unroll
  for (int r = 0; r < 4; ++r) {
    bool valid = (t + r - 3) >= 0;
    const uint4* src = (const uint4*)(Pqkv + (ptrdiff_t)(bt + r - 3) * PQK);
    uint4* dst = (uint4*)rows[r];
#pragma unroll
    for (int i = 0; i < 3; ++i) {
      int off = tid + i * 256;  // 0..767
      uint4 v;
      if (valid) v = src[off];
      else { v.x = 0; v.y = 0; v.z = 0; v.w = 0; }
      dst[off] = v;
    }
  }
  __syncthreads();

#pragma unroll
  for (int part = 0; part < 2; ++part) {
    const float* w = part ? wk : wq;
    float y[6]; float ss = 0.f;
#pragma unroll
    for (int jj = 0; jj < 6; ++jj) {
      int c = li + jj * 16;
      int ch = h * DK_ + c;
      float a = 0.f;
#pragma unroll
      for (int j = 0; j < KS_; ++j)
        a += bf2f(rows[j][part * KEYD + ch]) * w[ch * KS_ + j];
      float yv = a / (1.f + __expf(-a));
      y[jj] = yv; ss += yv * yv;
    }
    ss += __shfl_xor(ss, 1); ss += __shfl_xor(ss, 2);
    ss += __shfl_xor(ss, 4); ss += __shfl_xor(ss, 8);
    float rn = rsqrtf(ss + 1e-12f);
    u16* out = (part ? kc : qc) + (size_t)bt * KEYD + h * DK_;
#pragma unroll
    for (int jj = 0; jj < 6; ++jj) out[li + jj * 16] = f2bf(y[jj] * rn);
  }
  u16* vout = vc + (size_t)bt * VALD;
#pragma unroll
  for (int jj = 0; jj < 12; ++jj) {
    int c = tid + jj * 256;
    float a = 0.f;
#pragma unroll
    for (int j = 0; j < KS_; ++j)
      a += bf2f(rows[j][2 * KEYD + c]) * wv[c * KS_ + j];
    vout[c] = f2bf(a / (1.f + __expf(-a)));
  }
}

// ================= chunked gated-delta scan =================
__global__ __launch_bounds__(320) void chunk_prep(
    const u16* __restrict__ kc, u16* __restrict__ Uv /* = vc, in-place */,
    const float* __restrict__ gg, const float* __restrict__ beta,
    u16* __restrict__ Wg, float* __restrict__ Gcum,
    float* __restrict__ cdArr, float* __restrict__ lamArr) {
  __shared__ __align__(16) u16 ktL[64 * 104];
  __shared__ float AmL[64 * 68];
  __shared__ float glL[64], GclL[64], blL[64], DplL[64];
  int tid = threadIdx.x;
  int flat = blockIdx.x;
  int c = flat & 31, bh = flat >> 5, h = bh & 15, b = bh >> 4;
  int bT0 = b * T_ + c * 64;

  {
    const u32* kg = (const u32*)(kc + (size_t)bT0 * KEYD + h * DK_);
    for (int i = tid; i < 3072; i += 320) {
      int t = i / 48, dd = i - t * 48;
      ((u32*)ktL)[t * 52 + dd] = kg[(size_t)t * (KEYD / 2) + dd];
    }
  }
  if (tid < 64) {
    float g = gg[(size_t)(bT0 + tid) * H_ + h];
    float bv = beta[(size_t)(bT0 + tid) * H_ + h];
    float v = g;
#pragma unroll
    for (int off = 1; off < 64; off <<= 1) {
      float u = __shfl_up(v, off);
      if (tid >= off) v += u;
    }
    float g63 = __shfl(v, 63);
    glL[tid] = g; GclL[tid] = v; blL[tid] = bv; DplL[tid] = __expf(v - g);
    Gcum[(size_t)flat * 64 + tid] = v;
    cdArr[(size_t)flat * 64 + tid] = bv * __expf(g63 - v);
    if (tid == 63) lamArr[flat] = __expf(v);
  }
  __syncthreads();

  {
    int wave = tid >> 6, lane = tid & 63, l15 = lane & 15, l16 = lane >> 4;
    if (wave < 4) {
      f32x4 ac[4] = {};
#pragma unroll
      for (int ks = 0; ks < 3; ++ks) {
        bf16x8 a = *(const bf16x8*)&ktL[(wave * 16 + l15) * 104 + ks * 32 + l16 * 8];
#pragma unroll
        for (int n = 0; n < 4; ++n) {
          bf16x8 bb = *(const bf16x8*)&ktL[(n * 16 + l15) * 104 + ks * 32 + l16 * 8];
          ac[n] = __builtin_amdgcn_mfma_f32_16x16x32_bf16(a, bb, ac[n], 0, 0, 0);
        }
      }
#pragma unroll
      for (int n = 0; n < 4; ++n)
#pragma unroll
        for (int j = 0; j < 4; ++j) {
          int t = wave * 16 + l16 * 4 + j;
          int jj = n * 16 + l15;
          float val = 0.f;
          if (jj < t) val = __expf((GclL[t] - glL[t]) - GclL[jj]) * blL[jj] * ac[n][j];
          AmL[t * 68 + jj] = val;
        }
    }
  }
  __syncthreads();

  if (tid < 288) {
    int j = tid;
    float m[64];
    if (j < 192) {
      const u16* up = Uv + (size_t)bT0 * VALD + h * DV_ + j;
#pragma unroll
      for (int t = 0; t < 64; ++t) m[t] = bf2f(up[(size_t)t * VALD]);
    } else {
      int d = j - 192;
#pragma unroll
      for (int t = 0; t < 64; ++t) m[t] = DplL[t] * bf2f(ktL[t * 104 + d]);
    }
#pragma unroll
    for (int t0 = 0; t0 < 64; t0 += 4) {
      {
        f32x4 a1 = *(const f32x4*)&AmL[(t0 + 1) * 68 + t0];
        m[t0 + 1] -= a1[0] * m[t0];
        f32x4 a2 = *(const f32x4*)&AmL[(t0 + 2) * 68 + t0];
        m[t0 + 2] -= a2[0] * m[t0] + a2[1] * m[t0 + 1];
        f32x4 a3 = *(const f32x4*)&AmL[(t0 + 3) * 68 + t0];
        m[t0 + 3] -= a3[0] * m[t0] + a3[1] * m[t0 + 1] + a3[2] * m[t0 + 2];
      }
#pragma unroll
      for (int tp = t0 + 4; tp < 64; ++tp) {
        f32x4 a = *(const f32x4*)&AmL[tp * 68 + t0];
        m[tp] -= a[0] * m[t0] + a[1] * m[t0 + 1] + a[2] * m[t0 + 2] + a[3] * m[t0 + 3];
      }
    }
    if (j < 192) {
      u16* up = Uv + (size_t)bT0 * VALD + h * DV_ + j;
#pragma unroll
      for (int t = 0; t < 64; ++t) up[(size_t)t * VALD] = f2bf(m[t]);
    } else {
      int d = j - 192;
      u16* wp = Wg + (size_t)bT0 * KEYD + h * DK_ + d;
#pragma unroll
      for (int t = 0; t < 64; ++t) wp[(size_t)t * KEYD] = f2bf(m[t]);
    }
  }
}

// serial (MFMA + prefetch): grid = (bh 32) x (sl 12, 16 cols each) = 384 blocks.
// Wave w owns E-rows [16w,16w+16); S d-tiles: w, and 4+w for w<2 (static asymmetric).
// MFMA accumulation order per (t,col)/(d,col) tile identical to previous version.
__global__ __launch_bounds__(256) void serial_state(
    const u16* __restrict__ kc, const u16* __restrict__ Wg, u16* __restrict__ Ue,
    const float* __restrict__ cdArr, const float* __restrict__ lamArr,
    u16* __restrict__ Schk) {
  __shared__ __align__(16) u16 WtL[2][64 * 104];
  __shared__ __align__(16) u16 ktT[2][96 * 72];
  __shared__ __align__(16) u16 StH[16 * 104];
  __shared__ __align__(16) u16 StLo[16 * 104];
  __shared__ __align__(16) u16 EtH[16 * 72];
  __shared__ __align__(16) u16 EtLo[16 * 72];
  __shared__ float lamS[2];

  int tid = threadIdx.x, wave = tid >> 6, lane = tid & 63;
  int l15 = lane & 15, l16 = lane >> 4;
  int sl = blockIdx.x % 12, bh = blockIdx.x / 12, h = bh & 15, b = bh >> 4;
  int col0 = sl * 16;
  int st_t = tid >> 2, st_dd = (tid & 3) * 12;
  const bool hasB = (wave < 2);
  const int dtA = wave, dtB = 4 + wave;

  f32x4 Sf0 = {};
  f32x4 Sf1 = {};
  uint4 wreg[3], kreg[3];
  u16 ureg[4];
  float cdv[4];
  float lamReg;

#define PREFETCH(bT0p, flatp) { \
    const u32* wgp = (const u32*)(Wg + (size_t)((bT0p) + st_t) * KEYD + h * DK_) + st_dd; \
    const u32* kgp = (const u32*)(kc + (size_t)((bT0p) + st_t) * KEYD + h * DK_) + st_dd; \
    wreg[0] = ((const uint4*)wgp)[0]; wreg[1] = ((const uint4*)wgp)[1]; wreg[2] = ((const uint4*)wgp)[2]; \
    kreg[0] = ((const uint4*)kgp)[0]; kreg[1] = ((const uint4*)kgp)[1]; kreg[2] = ((const uint4*)kgp)[2]; \
    _Pragma("unroll") \
    for (int j = 0; j < 4; ++j) \
      ureg[j] = Ue[(size_t)((bT0p) + wave * 16 + l16 * 4 + j) * VALD + h * DV_ + col0 + l15]; \
    _Pragma("unroll") \
    for (int j = 0; j < 4; ++j) cdv[j] = cdArr[(size_t)(flatp) * 64 + wave * 16 + l16 * 4 + j]; \
    if (tid == 0) lamReg = lamArr[flatp]; \
  }

  PREFETCH(b * T_, bh * NC_);

  for (int c = 0; c < NC_; ++c) {
    int buf = c & 1;
    int flat = bh * NC_ + c;
    int bT0 = b * T_ + (c << 6);
    // ---- phase A: commit W/k tiles; publish S^T hi/lo + Schk snapshot ----
    {
      u32* wl = (u32*)&WtL[buf][0] + st_t * 52 + st_dd;
      ((uint4*)wl)[0] = wreg[0];
      *(uint4*)(wl + 4) = wreg[1];
      *(uint4*)(wl + 8) = wreg[2];
#pragma unroll
      for (int r = 0; r < 3; ++r) {
        u32 vals[4] = {kreg[r].x, kreg[r].y, kreg[r].z, kreg[r].w};
#pragma unroll
        for (int e = 0; e < 4; ++e) {
          int d = 2 * (st_dd + r * 4 + e);
          ktT[buf][d * 72 + st_t] = (u16)(vals[e] & 0xFFFFu);
          ktT[buf][(d + 1) * 72 + st_t] = (u16)(vals[e] >> 16);
        }
      }
      u16* schkRow = Schk + (size_t)flat * (DK_ * DV_) + (size_t)(col0 + l15) * DK_;
      {
        u16 hi0 = f2bf(Sf0[0]), hi1 = f2bf(Sf0[1]);
        u16 hi2 = f2bf(Sf0[2]), hi3 = f2bf(Sf0[3]);
        int dbase = dtA * 16 + l16 * 4;
        StH[l15 * 104 + dbase + 0] = hi0; StLo[l15 * 104 + dbase + 0] = f2bf(Sf0[0] - bf2f(hi0));
        StH[l15 * 104 + dbase + 1] = hi1; StLo[l15 * 104 + dbase + 1] = f2bf(Sf0[1] - bf2f(hi1));
        StH[l15 * 104 + dbase + 2] = hi2; StLo[l15 * 104 + dbase + 2] = f2bf(Sf0[2] - bf2f(hi2));
        StH[l15 * 104 + dbase + 3] = hi3; StLo[l15 * 104 + dbase + 3] = f2bf(Sf0[3] - bf2f(hi3));
        u32* ow = (u32*)(schkRow + dbase);
        ow[0] = ((u32)hi1 << 16) | hi0;
        ow[1] = ((u32)hi3 << 16) | hi2;
      }
      if (hasB) {
        u16 hi0 = f2bf(Sf1[0]), hi1 = f2bf(Sf1[1]);
        u16 hi2 = f2bf(Sf1[2]), hi3 = f2bf(Sf1[3]);
        int dbase = dtB * 16 + l16 * 4;
        StH[l15 * 104 + dbase + 0] = hi0; StLo[l15 * 104 + dbase + 0] = f2bf(Sf1[0] - bf2f(hi0));
        StH[l15 * 104 + dbase + 1] = hi1; StLo[l15 * 104 + dbase + 1] = f2bf(Sf1[1] - bf2f(hi1));
        StH[l15 * 104 + dbase + 2] = hi2; StLo[l15 * 104 + dbase + 2] = f2bf(Sf1[2] - bf2f(hi2));
        StH[l15 * 104 + dbase + 3] = hi3; StLo[l15 * 104 + dbase + 3] = f2bf(Sf1[3] - bf2f(hi3));
        u32* ow = (u32*)(schkRow + dbase);
        ow[0] = ((u32)hi1 << 16) | hi0;
        ow[1] = ((u32)hi3 << 16) | hi2;
      }
      if (tid == 0) lamS[buf] = lamReg;
    }
    __syncthreads();
    // ---- phase B: E-step (wave w: rows 16w..16w+15 x 16 cols) ----
    {
      f32x4 Ea = {};
#pragma unroll
      for (int ks = 0; ks < 3; ++ks) {
        bf16x8 a = *(const bf16x8*)&WtL[buf][(wave * 16 + l15) * 104 + ks * 32 + l16 * 8];
        bf16x8 bhv = *(const bf16x8*)&StH[l15 * 104 + ks * 32 + l16 * 8];
        bf16x8 blv = *(const bf16x8*)&StLo[l15 * 104 + ks * 32 + l16 * 8];
        Ea = __builtin_amdgcn_mfma_f32_16x16x32_bf16(a, bhv, Ea, 0, 0, 0);
        Ea = __builtin_amdgcn_mfma_f32_16x16x32_bf16(a, blv, Ea, 0, 0, 0);
      }
#pragma unroll
      for (int j = 0; j < 4; ++j) {
        int t = wave * 16 + l16 * 4 + j;
        float ev = bf2f(ureg[j]) - Ea[j];
        Ue[(size_t)(bT0 + t) * VALD + h * DV_ + col0 + l15] = f2bf(ev);
        float ep = cdv[j] * ev;
        u16 ehi = f2bf(ep);
        EtH[l15 * 72 + t] = ehi;
        EtLo[l15 * 72 + t] = f2bf(ep - bf2f(ehi));
      }
      if (c + 1 < NC_) PREFETCH(bT0 + 64, flat + 1);
    }
    __syncthreads();
    // ---- phase C: S-step ----
    {
      float lam = lamS[buf];
#pragma unroll
      for (int j = 0; j < 4; ++j) Sf0[j] *= lam;
      if (hasB) {
#pragma unroll
        for (int j = 0; j < 4; ++j) Sf1[j] *= lam;
      }
#pragma unroll
      for (int ks = 0; ks < 2; ++ks) {
        bf16x8 bhv = *(const bf16x8*)&EtH[l15 * 72 + ks * 32 + l16 * 8];
        bf16x8 blv = *(const bf16x8*)&EtLo[l15 * 72 + ks * 32 + l16 * 8];
        bf16x8 aA = *(const bf16x8*)&ktT[buf][(dtA * 16 + l15) * 72 + ks * 32 + l16 * 8];
        Sf0 = __builtin_amdgcn_mfma_f32_16x16x32_bf16(aA, bhv, Sf0, 0, 0, 0);
        Sf0 = __builtin_amdgcn_mfma_f32_16x16x32_bf16(aA, blv, Sf0, 0, 0, 0);
        if (hasB) {
          bf16x8 aB = *(const bf16x8*)&ktT[buf][(dtB * 16 + l15) * 72 + ks * 32 + l16 * 8];
          Sf1 = __builtin_amdgcn_mfma_f32_16x16x32_bf16(aB, bhv, Sf1, 0, 0, 0);
          Sf1 = __builtin_amdgcn_mfma_f32_16x16x32_bf16(aB, blv, Sf1, 0, 0, 0);
        }
      }
    }
  }
#undef PREFETCH
}

// pass3 (MFMA) + fused gated RMSNorm: onb = rmsnorm(O) * w * sigmoid(Pg).
__global__ __launch_bounds__(256) void chunk_out(
    const u16* __restrict__ qc, const u16* __restrict__ kc, const u16* __restrict__ Ee,
    const u16* __restrict__ Schk, const float* __restrict__ Gcum,
    const float* __restrict__ beta, const u16* __restrict__ Pg,
    const float* __restrict__ onw, u16* __restrict__ onb) {
  __shared__ __align__(16) char pool[65280];
  u16* qL   = (u16*)pool;              // [64][96]
  u16* BmL  = (u16*)(pool + 12288);    // [64][72]
  u16* BmLo = (u16*)(pool + 21504);    // [64][72]
  u16* kL   = (u16*)(pool + 30720);    // [64][96] (phase A)
  u16* StL  = (u16*)(pool + 30720);    // [96][104] (phase B)
  u16* EtL  = (u16*)(pool + 50688);    // [96][72]
  float* GclL = (float*)(pool + 64512);
  float* blL  = (float*)(pool + 64768);
  float* DlL  = (float*)(pool + 65024);
  u16* PgL  = (u16*)pool;              // [64][192] (epilogue; over qL/BmL/BmLo)
  float* wL = (float*)(pool + 24576);  // 192 f32 (epilogue)

  int tid = threadIdx.x, wave = tid >> 6, lane = tid & 63;
  int l15 = lane & 15, l16 = lane >> 4;
  int flat = blockIdx.x;
  int c = flat & 31, bh = flat >> 5, h = bh & 15, b = bh >> 4;
  int bT0 = b * T_ + c * 64;

  {
    const u32* qg = (const u32*)(qc + (size_t)bT0 * KEYD + h * DK_);
    const u32* kg = (const u32*)(kc + (size_t)bT0 * KEYD + h * DK_);
    for (int i = tid; i < 3072; i += 256) {
      int t = i / 48, dd = i - t * 48;
      ((u32*)qL)[t * 48 + dd] = qg[(size_t)t * (KEYD / 2) + dd];
      ((u32*)kL)[t * 48 + dd] = kg[(size_t)t * (KEYD / 2) + dd];
    }
    if (tid < 64) {
      float gv = Gcum[(size_t)flat * 64 + tid];
      GclL[tid] = gv;
      DlL[tid] = __expf(gv);
      blL[tid] = beta[(size_t)(bT0 + tid) * H_ + h];
    }
  }
  __syncthreads();

  {
    f32x4 bacc[4] = {};
#pragma unroll
    for (int kk = 0; kk < 3; ++kk) {
      bf16x8 aq = *(const bf16x8*)&qL[(wave * 16 + l15) * 96 + kk * 32 + l16 * 8];
#pragma unroll
      for (int n = 0; n < 4; ++n) {
        bf16x8 bk = *(const bf16x8*)&kL[(n * 16 + l15) * 96 + kk * 32 + l16 * 8];
        bacc[n] = __builtin_amdgcn_mfma_f32_16x16x32_bf16(aq, bk, bacc[n], 0, 0, 0);
      }
    }
#pragma unroll
    for (int n = 0; n < 4; ++n)
#pragma unroll
      for (int j = 0; j < 4; ++j) {
        int t = wave * 16 + l16 * 4 + j;
        int jj = n * 16 + l15;
        float val = 0.f;
        if (jj <= t) val = __expf(GclL[t] - GclL[jj]) * blL[jj] * bacc[n][j];
        u16 hi = f2bf(val);
        BmL[t * 72 + jj] = hi;
        BmLo[t * 72 + jj] = f2bf(val - bf2f(hi));
      }
  }
  __syncthreads();   // kL dead

  f32x4 oacc0[6] = {};
  f32x4 oacc1[6] = {};

#define HALFC(half, OACC) { \
    { \
      const u32* sg = (const u32*)(Schk + (size_t)flat * (DK_ * DV_) + (size_t)((half) * 96) * DK_); \
      for (int i = tid; i < 4608; i += 256) { \
        int cL = i / 48, dd = i - cL * 48; \
        ((u32*)&StL[cL * 104])[dd] = sg[cL * 48 + dd]; \
      } \
      const u32* eg = (const u32*)(Ee + (size_t)bT0 * VALD + h * DV_ + (half) * 96); \
      for (int i = tid; i < 3072; i += 256) { \
        int t = i / 48, dd = i - t * 48; \
        u32 w2 = eg[(size_t)t * (VALD / 2) + dd]; \
        EtL[(2 * dd) * 72 + t]     = (u16)(w2 & 0xFFFF); \
        EtL[(2 * dd + 1) * 72 + t] = (u16)(w2 >> 16); \
      } \
    } \
    __syncthreads(); \
    _Pragma("unroll") \
    for (int kk = 0; kk < 3; ++kk) { \
      bf16x8 aq = *(const bf16x8*)&qL[(wave * 16 + l15) * 96 + kk * 32 + l16 * 8]; \
      _Pragma("unroll") \
      for (int n = 0; n < 6; ++n) { \
        bf16x8 bs = *(const bf16x8*)&StL[(n * 16 + l15) * 104 + kk * 32 + l16 * 8]; \
        OACC[n] = __builtin_amdgcn_mfma_f32_16x16x32_bf16(aq, bs, OACC[n], 0, 0, 0); \
      } \
    } \
    _Pragma("unroll") \
    for (int n = 0; n < 6; ++n) \
      _Pragma("unroll") \
      for (int j = 0; j < 4; ++j) \
        OACC[n][j] *= DlL[wave * 16 + l16 * 4 + j]; \
    _Pragma("unroll") \
    for (int kk = 0; kk < 2; ++kk) { \
      bf16x8 ah = *(const bf16x8*)&BmL[(wave * 16 + l15) * 72 + kk * 32 + l16 * 8]; \
      bf16x8 al = *(const bf16x8*)&BmLo[(wave * 16 + l15) * 72 + kk * 32 + l16 * 8]; \
      _Pragma("unroll") \
      for (int n = 0; n < 6; ++n) { \
        bf16x8 be = *(const bf16x8*)&EtL[(n * 16 + l15) * 72 + kk * 32 + l16 * 8]; \
        OACC[n] = __builtin_amdgcn_mfma_f32_16x16x32_bf16(ah, be, OACC[n], 0, 0, 0); \
        OACC[n] = __builtin_amdgcn_mfma_f32_16x16x32_bf16(al, be, OACC[n], 0, 0, 0); \
      } \
    } \
    __syncthreads(); \
  }

  HALFC(0, oacc0);
  HALFC(1, oacc1);
#undef HALFC

  // ---- fused gated RMSNorm epilogue ----
  {
    const uint4* pgg = (const uint4*)(Pg + (size_t)bT0 * VALD + h * DV_);
    int tr = tid >> 2, q = tid & 3;
    uint4* dstRow = (uint4*)&PgL[tr * 192];
    const uint4* srcRow = (const uint4*)((const u16*)pgg + (size_t)tr * VALD);
#pragma unroll
    for (int ii = 0; ii < 6; ++ii)
      dstRow[q * 6 + ii] = srcRow[q * 6 + ii];
    if (tid < 192) wL[tid] = onw[tid];
  }
  __syncthreads();

  float ssv[4] = {0.f, 0.f, 0.f, 0.f};
#pragma unroll
  for (int n = 0; n < 6; ++n)
#pragma unroll
    for (int j = 0; j < 4; ++j) {
      float y0 = bf2f(f2bf(oacc0[n][j]));
      float y1 = bf2f(f2bf(oacc1[n][j]));
      ssv[j] += y0 * y0 + y1 * y1;
    }
#pragma unroll
  for (int j = 0; j < 4; ++j) {
    ssv[j] += __shfl_xor(ssv[j], 1); ssv[j] += __shfl_xor(ssv[j], 2);
    ssv[j] += __shfl_xor(ssv[j], 4); ssv[j] += __shfl_xor(ssv[j], 8);
  }
  float rmsv[4];
#pragma unroll
  for (int j = 0; j < 4; ++j) rmsv[j] = rsqrtf(ssv[j] * (1.f / DV_) + 1e-6f);

#define EPIL(OACC, half) { \
    _Pragma("unroll") \
    for (int n = 0; n < 6; ++n) \
      _Pragma("unroll") \
      for (int j = 0; j < 4; ++j) { \
        int t = wave * 16 + l16 * 4 + j; \
        int cc = (half) * 96 + n * 16 + l15; \
        float yv = bf2f(f2bf(OACC[n][j])); \
        float gv = bf2f(PgL[t * 192 + cc]); \
        float sig = 1.f / (1.f + __expf(-gv)); \
        onb[(size_t)(bT0 + t) * VALD + h * DV_ + cc] = f2bf(yv * rmsv[j] * wL[cc] * sig); \
      } \
  }
  EPIL(oacc0, 0);
  EPIL(oacc1, 1);
#undef EPIL
}

// ---------- launch ----------
extern "C" void kernel_launch(void* const* d_in, const int* in_sizes, int n_in,
                              void* d_out, int out_size, void* d_ws, size_t ws_size,
                              hipStream_t stream) {
  (void)in_sizes; (void)n_in; (void)out_size; (void)ws_size;
  const float* x      = (const float*)d_in[0];
  const float* Wq     = (const float*)d_in[1];
  const float* Wk     = (const float*)d_in[2];
  const float* Wv     = (const float*)d_in[3];
  const float* Wb     = (const float*)d_in[4];
  const float* Wa     = (const float*)d_in[5];
  const float* Wg     = (const float*)d_in[6];
  const float* Wo     = (const float*)d_in[7];
  const float* cqw    = (const float*)d_in[8];
  const float* ckw    = (const float*)d_in[9];
  const float* cvw    = (const float*)d_in[10];
  const float* A_log  = (const float*)d_in[11];
  const float* dt_bias= (const float*)d_in[12];
  const float* onw    = (const float*)d_in[13];
  float* out = (float*)d_out;

  char* ws = (char*)d_ws;
  u16*   xb    = (u16*)  (ws + 0);            // 16,777,216
  u16*   WT    = (u16*)  (ws + 16777216);     // 37,748,736
  u16*   qc    = (u16*)  (ws + 0);            // alias after gemm1
  u16*   kc    = (u16*)  (ws + 12582912);
  u16*   vc    = (u16*)  (ws + 25165824);     // also U -> E, in place
  u16*   Pqkv  = (u16*)  (ws + 54525952);     // 50,331,648
  u16*   Wbuf  = (u16*)  (ws + 54525952);     // alias after convs
  u16*   Schk  = (u16*)  (ws + 67108864);     // col-major [col][d]
  u16*   Pg    = (u16*)  (ws + 104857600);
  float* beta  = (float*)(ws + 155189248);
  float* gg    = (float*)(ws + 155451392);
  float* Gcum  = (float*)(ws + 155713536);
  float* cdArr = (float*)(ws + 155975680);
  float* lamArr= (float*)(ws + 156237824);
  u16*   onb   = (u16*)  (ws + 54525952);     // alias (after serial_state)
  u16*   WoT   = (u16*)  (ws + 79691776);     // alias (Pqkv dead)

  int n4 = B_ * T_ * D_ / 4;
  transpose_cast4<<<18432 + (n4 + 255) / 256, 256, 0, stream>>>(Wq, Wk, Wv, Wg, WT, x, xb, n4);

  gemm256<1><<<dim3(NPROJ / 256, (B_ * T_) / 256), 512, 0, stream>>>(
      xb, WT, Pqkv, Pg, nullptr, B_ * T_, NPROJ, D_, PQK, PQK, VALD);
  proj_bg<<<(B_ * T_) / 4, 256, 0, stream>>>(x, Wb, Wa, A_log, dt_bias, beta, gg);
  conv_qkv<<<B_ * T_, 256, 0, stream>>>(Pqkv, cqw, ckw, cvw, qc, kc, vc);

  chunk_prep<<<B_ * H_ * NC_, 320, 0, stream>>>(kc, vc, gg, beta, Wbuf, Gcum, cdArr, lamArr);
  serial_state<<<B_ * H_ * 12, 256, 0, stream>>>(kc, Wbuf, vc, cdArr, lamArr, Schk);
  chunk_out<<<B_ * H_ * NC_, 256, 0, stream>>>(qc, kc, vc, Schk, Gcum, beta, Pg, onw, onb);

  transpose_cast<<<dim3(64, 96), 256, 0, stream>>>(Wo, WoT, 3072, 2048);
  gemm_bt<0><<<dim3(D_ / 128, (B_ * T_) / 128), 256, 0, stream>>>(
      onb, WoT, nullptr, nullptr, out, B_ * T_, D_, VALD, 0, 0, 0);
}

// Round 15
// 561.728 us; speedup vs baseline: 1.0410x; 1.0410x over previous
//
#include <hip/hip_runtime.h>

#define B_ 2
#define T_ 2048
#define D_ 2048
#define H_ 16
#define DK_ 96
#define DV_ 192
#define KEYD 1536
#define VALD 3072
#define NPROJ 9216
#define PQK 6144     // Pqkv row width (q|k|v)
#define KS_ 4
#define C_ 64
#define NC_ 32       // T_/C_

typedef unsigned short u16;
typedef unsigned int u32;
typedef __bf16 bf16x8 __attribute__((ext_vector_type(8)));
typedef float f32x4 __attribute__((ext_vector_type(4)));

// ---------- helpers ----------
__device__ __forceinline__ u16 f2bf(float f) {
  unsigned u = __float_as_uint(f);
  u += 0x7FFF + ((u >> 16) & 1);
  return (u16)(u >> 16);
}
__device__ __forceinline__ float bf2f(u16 v) { return __uint_as_float((unsigned)v << 16); }
__device__ __forceinline__ float bflo(u32 w) { return __uint_as_float(w << 16); }
__device__ __forceinline__ float bfhi(u32 w) { return __uint_as_float(w & 0xFFFF0000u); }

__device__ __forceinline__ void gll16(const void* g, void* lds) {
  __builtin_amdgcn_global_load_lds(
      (const __attribute__((address_space(1))) void*)g,
      (__attribute__((address_space(3))) void*)lds, 16, 0, 0);
}

// ---------- casts / transposes ----------
__device__ __forceinline__ void tc_body(const float* __restrict__ src,
                                        u16* __restrict__ dst, int R, int C,
                                        int bx, int by, int tid) {
  __shared__ float tile[32][33];
  int tx = tid & 31, ty = tid >> 5;
  int c0 = bx * 32, r0 = by * 32;
#pragma unroll
  for (int j = 0; j < 4; ++j)
    tile[ty + j * 8][tx] = src[(size_t)(r0 + ty + j * 8) * C + c0 + tx];
  __syncthreads();
#pragma unroll
  for (int j = 0; j < 4; ++j)
    dst[(size_t)(c0 + ty + j * 8) * R + r0 + tx] = f2bf(tile[tx][ty + j * 8]);
}

__global__ __launch_bounds__(256) void transpose_cast(const float* __restrict__ src,
                                                      u16* __restrict__ dst, int R, int C) {
  tc_body(src, dst, R, C, blockIdx.x, blockIdx.y, threadIdx.x);
}

// fused: transpose Wq|Wk|Wv|Wg into WT + cast x -> xb (bit-identical to separate launches)
__global__ __launch_bounds__(256) void transpose_cast4(const float* __restrict__ Wq,
    const float* __restrict__ Wk, const float* __restrict__ Wv,
    const float* __restrict__ Wg, u16* __restrict__ WT,
    const float* __restrict__ x, u16* __restrict__ xb, int n4) {
  int id = blockIdx.x;
  if (id < 3072) {
    tc_body(Wq, WT, 2048, 1536, id % 48, id / 48, threadIdx.x);
  } else if (id < 6144) {
    id -= 3072;
    tc_body(Wk, WT + (size_t)1536 * 2048, 2048, 1536, id % 48, id / 48, threadIdx.x);
  } else if (id < 12288) {
    id -= 6144;
    tc_body(Wv, WT + (size_t)3072 * 2048, 2048, 3072, id % 96, id / 96, threadIdx.x);
  } else if (id < 18432) {
    id -= 12288;
    tc_body(Wg, WT + (size_t)6144 * 2048, 2048, 3072, id % 96, id / 96, threadIdx.x);
  } else {
    int i = (id - 18432) * 256 + threadIdx.x;
    if (i < n4) {
      float4 v = reinterpret_cast<const float4*>(x)[i];
      ushort4 o;
      o.x = f2bf(v.x); o.y = f2bf(v.y); o.z = f2bf(v.z); o.w = f2bf(v.w);
      reinterpret_cast<ushort4*>(xb)[i] = o;
    }
  }
}

// ============ 256x256 BK=64 GEMM, 4-phase/tile (round-10 proven, 200 us) ============
template <int OUT16>
__global__ __launch_bounds__(512, 2) void gemm256(const u16* __restrict__ A,
    const u16* __restrict__ BT, u16* __restrict__ C0, u16* __restrict__ C1,
    float* __restrict__ Cf, int M, int N, int K, int nsplit, int s0, int s1) {
  __shared__ u16 LA[2][256 * 64];
  __shared__ u16 LB[2][256 * 64];
  const int tid = threadIdx.x, wave = tid >> 6, lane = tid & 63;
  const int l15 = lane & 15, l16 = lane >> 4, x7 = l15 & 7;
  const int wr = wave >> 2, wc = wave & 3;
  const int m0 = blockIdx.y * 256, n0 = blockIdx.x * 256;
  const int r8 = lane >> 3;
  const int csrc = ((lane & 7) ^ r8) << 3;    // pre-swizzled source elem offset
  const int NKT = K >> 6;
  f32x4 acc[8][4] = {};

// A staged in mh-interleaved halves: half 0 = rows {0-63,128-191}, half 1 = {64-127,192-255}
#define STG_A(p, kt, half) { \
    const u16* As_ = A + (size_t)m0 * K + (size_t)(kt) * 64; \
    _Pragma("unroll") \
    for (int g = 0; g < 2; ++g) { \
      int rowb = g * 128 + (half) * 64 + wave * 8; \
      gll16(As_ + (size_t)(rowb + r8) * K + csrc, (char*)&LA[p][0] + rowb * 128); \
    } \
  }
#define STG_B(p, kt) { \
    const u16* Bs_ = BT + (size_t)n0 * K + (size_t)(kt) * 64; \
    _Pragma("unroll") \
    for (int j = 0; j < 4; ++j) { \
      int rowb = j * 64 + wave * 8; \
      gll16(Bs_ + (size_t)(rowb + r8) * K + csrc, (char*)&LB[p][0] + rowb * 128); \
    } \
  }

#define LDA8(p, mh, dst) { \
    _Pragma("unroll") \
    for (int mi = 0; mi < 4; ++mi) \
      _Pragma("unroll") \
      for (int kk = 0; kk < 2; ++kk) { \
        int row = wr * 128 + (mh) * 64 + mi * 16 + l15; \
        dst[mi * 2 + kk] = *(const bf16x8*)((const char*)&LA[p][0] + row * 128 + (((kk * 4 + l16) ^ x7) << 4)); \
      } \
  }
#define LDB4(p, nh, dst) { \
    _Pragma("unroll") \
    for (int ni = 0; ni < 2; ++ni) \
      _Pragma("unroll") \
      for (int kk = 0; kk < 2; ++kk) { \
        int row = wc * 64 + (nh) * 32 + ni * 16 + l15; \
        dst[ni * 2 + kk] = *(const bf16x8*)((const char*)&LB[p][0] + row * 128 + (((kk * 4 + l16) ^ x7) << 4)); \
      } \
  }

#define MMQ(AF, BF, mbase, nbase) { \
    __builtin_amdgcn_s_setprio(1); \
    _Pragma("unroll") \
    for (int mi = 0; mi < 4; ++mi) \
      _Pragma("unroll") \
      for (int ni = 0; ni < 2; ++ni) \
        _Pragma("unroll") \
        for (int kk = 0; kk < 2; ++kk) \
          acc[(mbase) + mi][(nbase) + ni] = __builtin_amdgcn_mfma_f32_16x16x32_bf16( \
              AF[mi * 2 + kk], BF[ni * 2 + kk], acc[(mbase) + mi][(nbase) + ni], 0, 0, 0); \
    __builtin_amdgcn_s_setprio(0); \
  }

#define BARR() __builtin_amdgcn_s_barrier()

  // prologue: stage tiles 0,1 fully; wait tile0 resident (tile1 stays in flight)
  STG_A(0, 0, 0); STG_A(0, 0, 1); STG_B(0, 0);
  if (NKT > 1) {
    STG_A(1, 1, 0); STG_A(1, 1, 1); STG_B(1, 1);
    asm volatile("s_waitcnt vmcnt(8)" ::: "memory");
  } else {
    asm volatile("s_waitcnt vmcnt(0)" ::: "memory");
  }
  BARR();

  bf16x8 afA[8], afB[8], bf0[4], bf1[4];
  for (int c = 0; c < NKT; ++c) {
    const int p = c & 1;
    const bool stg = (c + 2 < NKT);
    // ---- ph0: Q00 ----
    LDA8(p, 0, afA); LDB4(p, 0, bf0);
    BARR();
    MMQ(afA, bf0, 0, 0);
    BARR();
    // ---- ph1: Q01 ---- (stage A-half0 of c+2: A-mh0 rows read only at ph0)
    LDB4(p, 1, bf1);
    if (stg) STG_A(p, c + 2, 0);
    BARR();
    MMQ(afA, bf1, 0, 2);
    BARR();
    // ---- ph2: Q11 ---- (stage B full of c+2: B rows read only at ph0/ph1)
    LDA8(p, 1, afB);
    if (stg) STG_B(p, c + 2);
    BARR();
    MMQ(afB, bf1, 4, 2);
    BARR();
    // ---- ph3: Q10 ---- (stage A-half1; counted vmcnt once per tile)
    if (stg) {
      STG_A(p, c + 2, 1);
      asm volatile("s_waitcnt vmcnt(8)" ::: "memory");
    } else if (c + 1 < NKT) {
      asm volatile("s_waitcnt vmcnt(0)" ::: "memory");
    }
    BARR();
    MMQ(afB, bf0, 4, 0);
    BARR();
  }

#pragma unroll
  for (int mi = 0; mi < 8; ++mi)
#pragma unroll
    for (int ni = 0; ni < 4; ++ni)
#pragma unroll
      for (int j = 0; j < 4; ++j) {
        int row = m0 + wr * 128 + mi * 16 + l16 * 4 + j;
        int col = n0 + wc * 64 + ni * 16 + l15;
        float v = acc[mi][ni][j];
        if (OUT16) {
          if (col < nsplit) C0[(size_t)row * s0 + col] = f2bf(v);
          else              C1[(size_t)row * s1 + col - nsplit] = f2bf(v);
        } else {
          Cf[(size_t)row * N + col] = v;
        }
      }
#undef STG_A
#undef STG_B
#undef LDA8
#undef LDB4
#undef MMQ
#undef BARR
}

// ---------- bf16 MFMA GEMM (m97 structure, for gemm2): C = A[M,K] * BT[N,K]^T ----------
template <int OUT16>
__global__ __launch_bounds__(256) void gemm_bt(const u16* __restrict__ A,
                                               const u16* __restrict__ BT,
                                               u16* __restrict__ C0, u16* __restrict__ C1,
                                               float* __restrict__ Cf,
                                               int M, int N, int K, int nsplit, int s0, int s1) {
  __shared__ u16 As[128 * 32];
  __shared__ u16 Bs[128 * 32];
  int tid = threadIdx.x;
  int wave = tid >> 6, lane = tid & 63;
  int l15 = lane & 15, l16 = lane >> 4;
  int m0 = blockIdx.y * 128, n0 = blockIdx.x * 128;
  int wm = (wave >> 1) * 64, wn = (wave & 1) * 64;
  f32x4 acc[4][4] = {};
  int nkt = K >> 5;
  for (int kt = 0; kt < nkt; ++kt) {
    int k0 = kt << 5;
    __syncthreads();
#pragma unroll
    for (int rr = 0; rr < 2; ++rr) {
      int idx = tid + rr * 256;
      int row = idx >> 2, kc8 = (idx & 3) * 8;
      unsigned loff = (unsigned)(rr * 256 + wave * 64) * 16;
      gll16(A + (size_t)(m0 + row) * K + k0 + kc8, (char*)As + loff);
      gll16(BT + (size_t)(n0 + row) * K + k0 + kc8, (char*)Bs + loff);
    }
    __syncthreads();
    bf16x8 af[4], bfr[4];
#pragma unroll
    for (int i = 0; i < 4; ++i)
      af[i] = *reinterpret_cast<const bf16x8*>(&As[(wm + i * 16 + l15) * 32 + l16 * 8]);
#pragma unroll
    for (int i = 0; i < 4; ++i)
      bfr[i] = *reinterpret_cast<const bf16x8*>(&Bs[(wn + i * 16 + l15) * 32 + l16 * 8]);
#pragma unroll
    for (int mi = 0; mi < 4; ++mi)
#pragma unroll
      for (int ni = 0; ni < 4; ++ni)
        acc[mi][ni] = __builtin_amdgcn_mfma_f32_16x16x32_bf16(af[mi], bfr[ni], acc[mi][ni], 0, 0, 0);
  }
#pragma unroll
  for (int mi = 0; mi < 4; ++mi)
#pragma unroll
    for (int ni = 0; ni < 4; ++ni)
#pragma unroll
      for (int j = 0; j < 4; ++j) {
        int row = m0 + wm + mi * 16 + l16 * 4 + j;
        int col = n0 + wn + ni * 16 + l15;
        if (OUT16) {
          if (col < nsplit) C0[(size_t)row * s0 + col] = f2bf(acc[mi][ni][j]);
          else              C1[(size_t)row * s1 + col - nsplit] = f2bf(acc[mi][ni][j]);
        } else {
          Cf[(size_t)row * N + col] = acc[mi][ni][j];
        }
      }
}

// ---------- beta / g projections ----------
__global__ __launch_bounds__(256) void proj_bg(const float* __restrict__ x,
    const float* __restrict__ Wb, const float* __restrict__ Wa,
    const float* __restrict__ A_log, const float* __restrict__ dt_bias,
    float* __restrict__ beta, float* __restrict__ gg) {
  __shared__ float xs[4 * 2048];
  __shared__ float red[4][32][8];
  int tid = threadIdx.x;
  int r0 = blockIdx.x * 4;
  for (int i = tid; i < 4 * 2048; i += 256)
    xs[i] = x[(size_t)r0 * D_ + i];
  __syncthreads();
  int colg = tid & 31, ks = tid >> 5;
  const float* W = (colg < 16) ? Wb : Wa;
  int wc = colg & 15;
  float p0 = 0, p1 = 0, p2 = 0, p3 = 0;
  int kbeg = ks * 256;
  for (int k = kbeg; k < kbeg + 256; ++k) {
    float wv = W[k * H_ + wc];
    p0 += xs[k] * wv;
    p1 += xs[2048 + k] * wv;
    p2 += xs[4096 + k] * wv;
    p3 += xs[6144 + k] * wv;
  }
  red[0][colg][ks] = p0; red[1][colg][ks] = p1;
  red[2][colg][ks] = p2; red[3][colg][ks] = p3;
  __syncthreads();
  if (tid < 128) {
    int row = tid >> 5, col = tid & 31;
    float d = 0;
#pragma unroll
    for (int i = 0; i < 8; ++i) d += red[row][col][i];
    int r = r0 + row;
    if (col < 16) {
      beta[(size_t)r * H_ + col] = 1.f / (1.f + __expf(-d));
    } else {
      int hh = col - 16;
      float z = d + dt_bias[hh];
      float sp = (z > 20.f) ? z : log1pf(__expf(z));
      gg[(size_t)r * H_ + hh] = -__expf(A_log[hh]) * sp;
    }
  }
}

// ---------- fused conv(KS=4)+SiLU (+L2norm for q,k), LDS-staged rows ----------
__global__ __launch_bounds__(256) void conv_qkv(const u16* __restrict__ Pqkv,
    const float* __restrict__ wq, const float* __restrict__ wk, const float* __restrict__ wv,
    u16* __restrict__ qc, u16* __restrict__ kc, u16* __restrict__ vc) {
  __shared__ __align__(16) u16 rows[4][PQK];   // 48 KB
  int bt = blockIdx.x;
  int t = bt & (T_ - 1);
  int tid = threadIdx.x, h = tid >> 4, li = tid & 15;
#pragma unroll
  for (int r = 0; r < 4; ++r) {
    bool valid = (t + r - 3) >= 0;
    const uint4* src = (const uint4*)(Pqkv + (ptrdiff_t)(bt + r - 3) * PQK);
    uint4* dst = (uint4*)rows[r];
#pragma unroll
    for (int i = 0; i < 3; ++i) {
      int off = tid + i * 256;  // 0..767
      uint4 v;
      if (valid) v = src[off];
      else { v.x = 0; v.y = 0; v.z = 0; v.w = 0; }
      dst[off] = v;
    }
  }
  __syncthreads();

#pragma unroll
  for (int part = 0; part < 2; ++part) {
    const float* w = part ? wk : wq;
    float y[6]; float ss = 0.f;
#pragma unroll
    for (int jj = 0; jj < 6; ++jj) {
      int c = li + jj * 16;
      int ch = h * DK_ + c;
      float a = 0.f;
#pragma unroll
      for (int j = 0; j < KS_; ++j)
        a += bf2f(rows[j][part * KEYD + ch]) * w[ch * KS_ + j];
      float yv = a / (1.f + __expf(-a));
      y[jj] = yv; ss += yv * yv;
    }
    ss += __shfl_xor(ss, 1); ss += __shfl_xor(ss, 2);
    ss += __shfl_xor(ss, 4); ss += __shfl_xor(ss, 8);
    float rn = rsqrtf(ss + 1e-12f);
    u16* out = (part ? kc : qc) + (size_t)bt * KEYD + h * DK_;
#pragma unroll
    for (int jj = 0; jj < 6; ++jj) out[li + jj * 16] = f2bf(y[jj] * rn);
  }
  u16* vout = vc + (size_t)bt * VALD;
#pragma unroll
  for (int jj = 0; jj < 12; ++jj) {
    int c = tid + jj * 256;
    float a = 0.f;
#pragma unroll
    for (int j = 0; j < KS_; ++j)
      a += bf2f(rows[j][2 * KEYD + c]) * wv[c * KS_ + j];
    vout[c] = f2bf(a / (1.f + __expf(-a)));
  }
}

// ================= chunked gated-delta scan =================
__global__ __launch_bounds__(320) void chunk_prep(
    const u16* __restrict__ kc, u16* __restrict__ Uv /* = vc, in-place */,
    const float* __restrict__ gg, const float* __restrict__ beta,
    u16* __restrict__ Wg, float* __restrict__ Gcum,
    float* __restrict__ cdArr, float* __restrict__ lamArr) {
  __shared__ __align__(16) u16 ktL[64 * 104];
  __shared__ float AmL[64 * 68];
  __shared__ float glL[64], GclL[64], blL[64], DplL[64];
  int tid = threadIdx.x;
  int flat = blockIdx.x;
  int c = flat & 31, bh = flat >> 5, h = bh & 15, b = bh >> 4;
  int bT0 = b * T_ + c * 64;

  {
    const u32* kg = (const u32*)(kc + (size_t)bT0 * KEYD + h * DK_);
    for (int i = tid; i < 3072; i += 320) {
      int t = i / 48, dd = i - t * 48;
      ((u32*)ktL)[t * 52 + dd] = kg[(size_t)t * (KEYD / 2) + dd];
    }
  }
  if (tid < 64) {
    float g = gg[(size_t)(bT0 + tid) * H_ + h];
    float bv = beta[(size_t)(bT0 + tid) * H_ + h];
    float v = g;
#pragma unroll
    for (int off = 1; off < 64; off <<= 1) {
      float u = __shfl_up(v, off);
      if (tid >= off) v += u;
    }
    float g63 = __shfl(v, 63);
    glL[tid] = g; GclL[tid] = v; blL[tid] = bv; DplL[tid] = __expf(v - g);
    Gcum[(size_t)flat * 64 + tid] = v;
    cdArr[(size_t)flat * 64 + tid] = bv * __expf(g63 - v);
    if (tid == 63) lamArr[flat] = __expf(v);
  }
  __syncthreads();

  {
    int wave = tid >> 6, lane = tid & 63, l15 = lane & 15, l16 = lane >> 4;
    if (wave < 4) {
      f32x4 ac[4] = {};
#pragma unroll
      for (int ks = 0; ks < 3; ++ks) {
        bf16x8 a = *(const bf16x8*)&ktL[(wave * 16 + l15) * 104 + ks * 32 + l16 * 8];
#pragma unroll
        for (int n = 0; n < 4; ++n) {
          bf16x8 bb = *(const bf16x8*)&ktL[(n * 16 + l15) * 104 + ks * 32 + l16 * 8];
          ac[n] = __builtin_amdgcn_mfma_f32_16x16x32_bf16(a, bb, ac[n], 0, 0, 0);
        }
      }
#pragma unroll
      for (int n = 0; n < 4; ++n)
#pragma unroll
        for (int j = 0; j < 4; ++j) {
          int t = wave * 16 + l16 * 4 + j;
          int jj = n * 16 + l15;
          float val = 0.f;
          if (jj < t) val = __expf((GclL[t] - glL[t]) - GclL[jj]) * blL[jj] * ac[n][j];
          AmL[t * 68 + jj] = val;
        }
    }
  }
  __syncthreads();

  if (tid < 288) {
    int j = tid;
    float m[64];
    if (j < 192) {
      const u16* up = Uv + (size_t)bT0 * VALD + h * DV_ + j;
#pragma unroll
      for (int t = 0; t < 64; ++t) m[t] = bf2f(up[(size_t)t * VALD]);
    } else {
      int d = j - 192;
#pragma unroll
      for (int t = 0; t < 64; ++t) m[t] = DplL[t] * bf2f(ktL[t * 104 + d]);
    }
#pragma unroll
    for (int t0 = 0; t0 < 64; t0 += 4) {
      {
        f32x4 a1 = *(const f32x4*)&AmL[(t0 + 1) * 68 + t0];
        m[t0 + 1] -= a1[0] * m[t0];
        f32x4 a2 = *(const f32x4*)&AmL[(t0 + 2) * 68 + t0];
        m[t0 + 2] -= a2[0] * m[t0] + a2[1] * m[t0 + 1];
        f32x4 a3 = *(const f32x4*)&AmL[(t0 + 3) * 68 + t0];
        m[t0 + 3] -= a3[0] * m[t0] + a3[1] * m[t0 + 1] + a3[2] * m[t0 + 2];
      }
#pragma unroll
      for (int tp = t0 + 4; tp < 64; ++tp) {
        f32x4 a = *(const f32x4*)&AmL[tp * 68 + t0];
        m[tp] -= a[0] * m[t0] + a[1] * m[t0 + 1] + a[2] * m[t0 + 2] + a[3] * m[t0 + 3];
      }
    }
    if (j < 192) {
      u16* up = Uv + (size_t)bT0 * VALD + h * DV_ + j;
#pragma unroll
      for (int t = 0; t < 64; ++t) up[(size_t)t * VALD] = f2bf(m[t]);
    } else {
      int d = j - 192;
      u16* wp = Wg + (size_t)bT0 * KEYD + h * DK_ + d;
#pragma unroll
      for (int t = 0; t < 64; ++t) wp[(size_t)t * KEYD] = f2bf(m[t]);
    }
  }
}

// serial (MFMA + prefetch): grid = (bh 32) x (jq 6, 32 cols each).
// Schk written COL-MAJOR: Schk[flat][col][d].
__global__ __launch_bounds__(256) void serial_state(
    const u16* __restrict__ kc, const u16* __restrict__ Wg, u16* __restrict__ Ue,
    const float* __restrict__ cdArr, const float* __restrict__ lamArr,
    u16* __restrict__ Schk) {
  __shared__ __align__(16) u16 WtL[2][64 * 104];
  __shared__ __align__(16) u16 ktT[2][96 * 72];
  __shared__ __align__(16) u16 StH[32 * 104];
  __shared__ __align__(16) u16 StLo[32 * 104];
  __shared__ __align__(16) u16 EtH[32 * 72];
  __shared__ __align__(16) u16 EtLo[32 * 72];
  __shared__ float lamS[2];

  int tid = threadIdx.x, wave = tid >> 6, lane = tid & 63;
  int l15 = lane & 15, l16 = lane >> 4;
  int jq = blockIdx.x % 6, bh = blockIdx.x / 6, h = bh & 15, b = bh >> 4;
  int col0 = jq * 32;
  int ntS = wave & 1, m3 = 3 * (wave >> 1);
  int st_t = tid >> 2, st_dd = (tid & 3) * 12;

  f32x4 Sf[3] = {};
  uint4 wreg[3], kreg[3];
  u16 ureg[2][4];
  float cdv[4];
  float lamReg;

#define PREFETCH(bT0p, flatp) { \
    const u32* wgp = (const u32*)(Wg + (size_t)((bT0p) + st_t) * KEYD + h * DK_) + st_dd; \
    const u32* kgp = (const u32*)(kc + (size_t)((bT0p) + st_t) * KEYD + h * DK_) + st_dd; \
    wreg[0] = ((const uint4*)wgp)[0]; wreg[1] = ((const uint4*)wgp)[1]; wreg[2] = ((const uint4*)wgp)[2]; \
    kreg[0] = ((const uint4*)kgp)[0]; kreg[1] = ((const uint4*)kgp)[1]; kreg[2] = ((const uint4*)kgp)[2]; \
    _Pragma("unroll") \
    for (int ni = 0; ni < 2; ++ni) \
      _Pragma("unroll") \
      for (int j = 0; j < 4; ++j) \
        ureg[ni][j] = Ue[(size_t)((bT0p) + wave * 16 + l16 * 4 + j) * VALD + h * DV_ + col0 + ni * 16 + l15]; \
    _Pragma("unroll") \
    for (int j = 0; j < 4; ++j) cdv[j] = cdArr[(size_t)(flatp) * 64 + wave * 16 + l16 * 4 + j]; \
    if (tid == 0) lamReg = lamArr[flatp]; \
  }

  PREFETCH(b * T_, bh * NC_);

  for (int c = 0; c < NC_; ++c) {
    int buf = c & 1;
    int flat = bh * NC_ + c;
    int bT0 = b * T_ + (c << 6);
    // ---- phase A ----
    {
      u32* wl = (u32*)&WtL[buf][0] + st_t * 52 + st_dd;
      ((uint4*)wl)[0] = wreg[0];
      *(uint4*)(wl + 4) = wreg[1];
      *(uint4*)(wl + 8) = wreg[2];
#pragma unroll
      for (int r = 0; r < 3; ++r) {
        u32 vals[4] = {kreg[r].x, kreg[r].y, kreg[r].z, kreg[r].w};
#pragma unroll
        for (int e = 0; e < 4; ++e) {
          int d = 2 * (st_dd + r * 4 + e);
          ktT[buf][d * 72 + st_t] = (u16)(vals[e] & 0xFFFFu);
          ktT[buf][(d + 1) * 72 + st_t] = (u16)(vals[e] >> 16);
        }
      }
      int cl = ntS * 16 + l15;
      u16* schkRow = Schk + (size_t)flat * (DK_ * DV_) + (size_t)(col0 + cl) * DK_;
#pragma unroll
      for (int i = 0; i < 3; ++i) {
        u16 hi0 = f2bf(Sf[i][0]), hi1 = f2bf(Sf[i][1]);
        u16 hi2 = f2bf(Sf[i][2]), hi3 = f2bf(Sf[i][3]);
        int dbase = (m3 + i) * 16 + l16 * 4;
        StH[cl * 104 + dbase + 0] = hi0; StLo[cl * 104 + dbase + 0] = f2bf(Sf[i][0] - bf2f(hi0));
        StH[cl * 104 + dbase + 1] = hi1; StLo[cl * 104 + dbase + 1] = f2bf(Sf[i][1] - bf2f(hi1));
        StH[cl * 104 + dbase + 2] = hi2; StLo[cl * 104 + dbase + 2] = f2bf(Sf[i][2] - bf2f(hi2));
        StH[cl * 104 + dbase + 3] = hi3; StLo[cl * 104 + dbase + 3] = f2bf(Sf[i][3] - bf2f(hi3));
        u32* ow = (u32*)(schkRow + dbase);
        ow[0] = ((u32)hi1 << 16) | hi0;
        ow[1] = ((u32)hi3 << 16) | hi2;
      }
      if (tid == 0) lamS[buf] = lamReg;
    }
    __syncthreads();
    // ---- phase B: E-step ----
    {
      f32x4 Ea[2] = {};
#pragma unroll
      for (int ks = 0; ks < 3; ++ks) {
        bf16x8 a = *(const bf16x8*)&WtL[buf][(wave * 16 + l15) * 104 + ks * 32 + l16 * 8];
#pragma unroll
        for (int ni = 0; ni < 2; ++ni) {
          bf16x8 bhv = *(const bf16x8*)&StH[(ni * 16 + l15) * 104 + ks * 32 + l16 * 8];
          bf16x8 blv = *(const bf16x8*)&StLo[(ni * 16 + l15) * 104 + ks * 32 + l16 * 8];
          Ea[ni] = __builtin_amdgcn_mfma_f32_16x16x32_bf16(a, bhv, Ea[ni], 0, 0, 0);
          Ea[ni] = __builtin_amdgcn_mfma_f32_16x16x32_bf16(a, blv, Ea[ni], 0, 0, 0);
        }
      }
#pragma unroll
      for (int ni = 0; ni < 2; ++ni)
#pragma unroll
        for (int j = 0; j < 4; ++j) {
          int t = wave * 16 + l16 * 4 + j;
          float ev = bf2f(ureg[ni][j]) - Ea[ni][j];
          Ue[(size_t)(bT0 + t) * VALD + h * DV_ + col0 + ni * 16 + l15] = f2bf(ev);
          float ep = cdv[j] * ev;
          u16 ehi = f2bf(ep);
          int cl = ni * 16 + l15;
          EtH[cl * 72 + t] = ehi;
          EtLo[cl * 72 + t] = f2bf(ep - bf2f(ehi));
        }
      if (c + 1 < NC_) PREFETCH(bT0 + 64, flat + 1);
    }
    __syncthreads();
    // ---- phase C: S-step ----
    {
      float lam = lamS[buf];
#pragma unroll
      for (int i = 0; i < 3; ++i)
#pragma unroll
        for (int j = 0; j < 4; ++j) Sf[i][j] *= lam;
#pragma unroll
      for (int ks = 0; ks < 2; ++ks) {
        bf16x8 bhv = *(const bf16x8*)&EtH[(ntS * 16 + l15) * 72 + ks * 32 + l16 * 8];
        bf16x8 blv = *(const bf16x8*)&EtLo[(ntS * 16 + l15) * 72 + ks * 32 + l16 * 8];
#pragma unroll
        for (int i = 0; i < 3; ++i) {
          bf16x8 a = *(const bf16x8*)&ktT[buf][((m3 + i) * 16 + l15) * 72 + ks * 32 + l16 * 8];
          Sf[i] = __builtin_amdgcn_mfma_f32_16x16x32_bf16(a, bhv, Sf[i], 0, 0, 0);
          Sf[i] = __builtin_amdgcn_mfma_f32_16x16x32_bf16(a, blv, Sf[i], 0, 0, 0);
        }
      }
    }
  }
#undef PREFETCH
}

// pass3 (MFMA) + fused gated RMSNorm: onb = rmsnorm(O) * w * sigmoid(Pg).
__global__ __launch_bounds__(256) void chunk_out(
    const u16* __restrict__ qc, const u16* __restrict__ kc, const u16* __restrict__ Ee,
    const u16* __restrict__ Schk, const float* __restrict__ Gcum,
    const float* __restrict__ beta, const u16* __restrict__ Pg,
    const float* __restrict__ onw, u16* __restrict__ onb) {
  __shared__ __align__(16) char pool[65280];
  u16* qL   = (u16*)pool;              // [64][96]
  u16* BmL  = (u16*)(pool + 12288);    // [64][72]
  u16* BmLo = (u16*)(pool + 21504);    // [64][72]
  u16* kL   = (u16*)(pool + 30720);    // [64][96] (phase A)
  u16* StL  = (u16*)(pool + 30720);    // [96][104] (phase B)
  u16* EtL  = (u16*)(pool + 50688);    // [96][72]
  float* GclL = (float*)(pool + 64512);
  float* blL  = (float*)(pool + 64768);
  float* DlL  = (float*)(pool + 65024);
  u16* PgL  = (u16*)pool;              // [64][192] (epilogue; over qL/BmL/BmLo)
  float* wL = (float*)(pool + 24576);  // 192 f32 (epilogue)

  int tid = threadIdx.x, wave = tid >> 6, lane = tid & 63;
  int l15 = lane & 15, l16 = lane >> 4;
  int flat = blockIdx.x;
  int c = flat & 31, bh = flat >> 5, h = bh & 15, b = bh >> 4;
  int bT0 = b * T_ + c * 64;

  {
    const u32* qg = (const u32*)(qc + (size_t)bT0 * KEYD + h * DK_);
    const u32* kg = (const u32*)(kc + (size_t)bT0 * KEYD + h * DK_);
    for (int i = tid; i < 3072; i += 256) {
      int t = i / 48, dd = i - t * 48;
      ((u32*)qL)[t * 48 + dd] = qg[(size_t)t * (KEYD / 2) + dd];
      ((u32*)kL)[t * 48 + dd] = kg[(size_t)t * (KEYD / 2) + dd];
    }
    if (tid < 64) {
      float gv = Gcum[(size_t)flat * 64 + tid];
      GclL[tid] = gv;
      DlL[tid] = __expf(gv);
      blL[tid] = beta[(size_t)(bT0 + tid) * H_ + h];
    }
  }
  __syncthreads();

  {
    f32x4 bacc[4] = {};
#pragma unroll
    for (int kk = 0; kk < 3; ++kk) {
      bf16x8 aq = *(const bf16x8*)&qL[(wave * 16 + l15) * 96 + kk * 32 + l16 * 8];
#pragma unroll
      for (int n = 0; n < 4; ++n) {
        bf16x8 bk = *(const bf16x8*)&kL[(n * 16 + l15) * 96 + kk * 32 + l16 * 8];
        bacc[n] = __builtin_amdgcn_mfma_f32_16x16x32_bf16(aq, bk, bacc[n], 0, 0, 0);
      }
    }
#pragma unroll
    for (int n = 0; n < 4; ++n)
#pragma unroll
      for (int j = 0; j < 4; ++j) {
        int t = wave * 16 + l16 * 4 + j;
        int jj = n * 16 + l15;
        float val = 0.f;
        if (jj <= t) val = __expf(GclL[t] - GclL[jj]) * blL[jj] * bacc[n][j];
        u16 hi = f2bf(val);
        BmL[t * 72 + jj] = hi;
        BmLo[t * 72 + jj] = f2bf(val - bf2f(hi));
      }
  }
  __syncthreads();   // kL dead

  f32x4 oacc0[6] = {};
  f32x4 oacc1[6] = {};

#define HALFC(half, OACC) { \
    { \
      const u32* sg = (const u32*)(Schk + (size_t)flat * (DK_ * DV_) + (size_t)((half) * 96) * DK_); \
      for (int i = tid; i < 4608; i += 256) { \
        int cL = i / 48, dd = i - cL * 48; \
        ((u32*)&StL[cL * 104])[dd] = sg[cL * 48 + dd]; \
      } \
      const u32* eg = (const u32*)(Ee + (size_t)bT0 * VALD + h * DV_ + (half) * 96); \
      for (int i = tid; i < 3072; i += 256) { \
        int t = i / 48, dd = i - t * 48; \
        u32 w2 = eg[(size_t)t * (VALD / 2) + dd]; \
        EtL[(2 * dd) * 72 + t]     = (u16)(w2 & 0xFFFF); \
        EtL[(2 * dd + 1) * 72 + t] = (u16)(w2 >> 16); \
      } \
    } \
    __syncthreads(); \
    _Pragma("unroll") \
    for (int kk = 0; kk < 3; ++kk) { \
      bf16x8 aq = *(const bf16x8*)&qL[(wave * 16 + l15) * 96 + kk * 32 + l16 * 8]; \
      _Pragma("unroll") \
      for (int n = 0; n < 6; ++n) { \
        bf16x8 bs = *(const bf16x8*)&StL[(n * 16 + l15) * 104 + kk * 32 + l16 * 8]; \
        OACC[n] = __builtin_amdgcn_mfma_f32_16x16x32_bf16(aq, bs, OACC[n], 0, 0, 0); \
      } \
    } \
    _Pragma("unroll") \
    for (int n = 0; n < 6; ++n) \
      _Pragma("unroll") \
      for (int j = 0; j < 4; ++j) \
        OACC[n][j] *= DlL[wave * 16 + l16 * 4 + j]; \
    _Pragma("unroll") \
    for (int kk = 0; kk < 2; ++kk) { \
      bf16x8 ah = *(const bf16x8*)&BmL[(wave * 16 + l15) * 72 + kk * 32 + l16 * 8]; \
      bf16x8 al = *(const bf16x8*)&BmLo[(wave * 16 + l15) * 72 + kk * 32 + l16 * 8]; \
      _Pragma("unroll") \
      for (int n = 0; n < 6; ++n) { \
        bf16x8 be = *(const bf16x8*)&EtL[(n * 16 + l15) * 72 + kk * 32 + l16 * 8]; \
        OACC[n] = __builtin_amdgcn_mfma_f32_16x16x32_bf16(ah, be, OACC[n], 0, 0, 0); \
        OACC[n] = __builtin_amdgcn_mfma_f32_16x16x32_bf16(al, be, OACC[n], 0, 0, 0); \
      } \
    } \
    __syncthreads(); \
  }

  HALFC(0, oacc0);
  HALFC(1, oacc1);
#undef HALFC

  // ---- fused gated RMSNorm epilogue ----
  {
    const uint4* pgg = (const uint4*)(Pg + (size_t)bT0 * VALD + h * DV_);
    int tr = tid >> 2, q = tid & 3;
    uint4* dstRow = (uint4*)&PgL[tr * 192];
    const uint4* srcRow = (const uint4*)((const u16*)pgg + (size_t)tr * VALD);
#pragma unroll
    for (int ii = 0; ii < 6; ++ii)
      dstRow[q * 6 + ii] = srcRow[q * 6 + ii];
    if (tid < 192) wL[tid] = onw[tid];
  }
  __syncthreads();

  float ssv[4] = {0.f, 0.f, 0.f, 0.f};
#pragma unroll
  for (int n = 0; n < 6; ++n)
#pragma unroll
    for (int j = 0; j < 4; ++j) {
      float y0 = bf2f(f2bf(oacc0[n][j]));
      float y1 = bf2f(f2bf(oacc1[n][j]));
      ssv[j] += y0 * y0 + y1 * y1;
    }
#pragma unroll
  for (int j = 0; j < 4; ++j) {
    ssv[j] += __shfl_xor(ssv[j], 1); ssv[j] += __shfl_xor(ssv[j], 2);
    ssv[j] += __shfl_xor(ssv[j], 4); ssv[j] += __shfl_xor(ssv[j], 8);
  }
  float rmsv[4];
#pragma unroll
  for (int j = 0; j < 4; ++j) rmsv[j] = rsqrtf(ssv[j] * (1.f / DV_) + 1e-6f);

#define EPIL(OACC, half) { \
    _Pragma("unroll") \
    for (int n = 0; n < 6; ++n) \
      _Pragma("unroll") \
      for (int j = 0; j < 4; ++j) { \
        int t = wave * 16 + l16 * 4 + j; \
        int cc = (half) * 96 + n * 16 + l15; \
        float yv = bf2f(f2bf(OACC[n][j])); \
        float gv = bf2f(PgL[t * 192 + cc]); \
        float sig = 1.f / (1.f + __expf(-gv)); \
        onb[(size_t)(bT0 + t) * VALD + h * DV_ + cc] = f2bf(yv * rmsv[j] * wL[cc] * sig); \
      } \
  }
  EPIL(oacc0, 0);
  EPIL(oacc1, 1);
#undef EPIL
}

// ---------- launch ----------
extern "C" void kernel_launch(void* const* d_in, const int* in_sizes, int n_in,
                              void* d_out, int out_size, void* d_ws, size_t ws_size,
                              hipStream_t stream) {
  (void)in_sizes; (void)n_in; (void)out_size; (void)ws_size;
  const float* x      = (const float*)d_in[0];
  const float* Wq     = (const float*)d_in[1];
  const float* Wk     = (const float*)d_in[2];
  const float* Wv     = (const float*)d_in[3];
  const float* Wb     = (const float*)d_in[4];
  const float* Wa     = (const float*)d_in[5];
  const float* Wg     = (const float*)d_in[6];
  const float* Wo     = (const float*)d_in[7];
  const float* cqw    = (const float*)d_in[8];
  const float* ckw    = (const float*)d_in[9];
  const float* cvw    = (const float*)d_in[10];
  const float* A_log  = (const float*)d_in[11];
  const float* dt_bias= (const float*)d_in[12];
  const float* onw    = (const float*)d_in[13];
  float* out = (float*)d_out;

  char* ws = (char*)d_ws;
  u16*   xb    = (u16*)  (ws + 0);            // 16,777,216
  u16*   WT    = (u16*)  (ws + 16777216);     // 37,748,736
  u16*   qc    = (u16*)  (ws + 0);            // alias after gemm1
  u16*   kc    = (u16*)  (ws + 12582912);
  u16*   vc    = (u16*)  (ws + 25165824);     // also U -> E, in place
  u16*   Pqkv  = (u16*)  (ws + 54525952);     // 50,331,648
  u16*   Wbuf  = (u16*)  (ws + 54525952);     // alias after convs
  u16*   Schk  = (u16*)  (ws + 67108864);     // col-major [col][d]
  u16*   Pg    = (u16*)  (ws + 104857600);
  float* beta  = (float*)(ws + 155189248);
  float* gg    = (float*)(ws + 155451392);
  float* Gcum  = (float*)(ws + 155713536);
  float* cdArr = (float*)(ws + 155975680);
  float* lamArr= (float*)(ws + 156237824);
  u16*   onb   = (u16*)  (ws + 54525952);     // alias (after serial_state)
  u16*   WoT   = (u16*)  (ws + 79691776);     // alias (Pqkv dead)

  int n4 = B_ * T_ * D_ / 4;
  transpose_cast4<<<18432 + (n4 + 255) / 256, 256, 0, stream>>>(Wq, Wk, Wv, Wg, WT, x, xb, n4);

  gemm256<1><<<dim3(NPROJ / 256, (B_ * T_) / 256), 512, 0, stream>>>(
      xb, WT, Pqkv, Pg, nullptr, B_ * T_, NPROJ, D_, PQK, PQK, VALD);
  proj_bg<<<(B_ * T_) / 4, 256, 0, stream>>>(x, Wb, Wa, A_log, dt_bias, beta, gg);
  conv_qkv<<<B_ * T_, 256, 0, stream>>>(Pqkv, cqw, ckw, cvw, qc, kc, vc);

  chunk_prep<<<B_ * H_ * NC_, 320, 0, stream>>>(kc, vc, gg, beta, Wbuf, Gcum, cdArr, lamArr);
  serial_state<<<B_ * H_ * 6, 256, 0, stream>>>(kc, Wbuf, vc, cdArr, lamArr, Schk);
  chunk_out<<<B_ * H_ * NC_, 256, 0, stream>>>(qc, kc, vc, Schk, Gcum, beta, Pg, onw, onb);

  transpose_cast<<<dim3(64, 96), 256, 0, stream>>>(Wo, WoT, 3072, 2048);
  gemm_bt<0><<<dim3(D_ / 128, (B_ * T_) / 128), 256, 0, stream>>>(
      onb, WoT, nullptr, nullptr, out, B_ * T_, D_, VALD, 0, 0, 0);
}